// Round 4
// baseline (415.456 us; speedup 1.0000x reference)
//
#include <hip/hip_runtime.h>
#include <math.h>

#define PI_HALF 1.57079632679489662f

__device__ __forceinline__ float fast_tanh(float x) {
    float e = __expf(2.f * x);
    return 1.f - 2.f * __builtin_amdgcn_rcpf(e + 1.f);
}

// ---------------- 4-qubit state helpers (compile-time masks -> registers) ----
// wire w (0..3) maps to amplitude-index bit (3-w), i.e. mask = 8 >> w.

__device__ __forceinline__ void init_state(float sr[16], float si[16]) {
#pragma unroll
    for (int i = 0; i < 16; ++i) { sr[i] = 0.f; si[i] = 0.f; }
    sr[0] = 1.f;
}

template<int M>
__device__ __forceinline__ void ry_g(float sr[16], float si[16], float c, float s) {
#pragma unroll
    for (int i = 0; i < 16; ++i) {
        if (i & M) continue;
        const int j = i | M;
        float ar = sr[i], ai = si[i], br = sr[j], bi = si[j];
        sr[i] = c * ar - s * br;  si[i] = c * ai - s * bi;
        sr[j] = s * ar + c * br;  si[j] = s * ai + c * bi;
    }
}

template<int M>
__device__ __forceinline__ void had_g(float sr[16], float si[16]) {
    const float r = 0.70710678118654752f;
#pragma unroll
    for (int i = 0; i < 16; ++i) {
        if (i & M) continue;
        const int j = i | M;
        float ar = sr[i], ai = si[i], br = sr[j], bi = si[j];
        sr[i] = (ar + br) * r;  si[i] = (ai + bi) * r;
        sr[j] = (ar - br) * r;  si[j] = (ai - bi) * r;
    }
}

template<int MC, int MT>
__device__ __forceinline__ void cnot_g(float sr[16], float si[16]) {
#pragma unroll
    for (int i = 0; i < 16; ++i) {
        if (!(i & MC) || (i & MT)) continue;
        const int j = i | MT;
        float tr = sr[i], ti = si[i];
        sr[i] = sr[j]; si[i] = si[j];
        sr[j] = tr;    si[j] = ti;
    }
}

template<int MC, int MT>
__device__ __forceinline__ void cry_g(float sr[16], float si[16], float c, float s) {
#pragma unroll
    for (int i = 0; i < 16; ++i) {
        if (!(i & MC) || (i & MT)) continue;
        const int j = i | MT;
        float ar = sr[i], ai = si[i], br = sr[j], bi = si[j];
        sr[i] = c * ar - s * br;  si[i] = c * ai - s * bi;
        sr[j] = s * ar + c * br;  si[j] = s * ai + c * bi;
    }
}

// Rot gate from a precomputed 8-float matrix {u00r,u00i,u01r,u01i,u10r,u10i,u11r,u11i}
template<int M>
__device__ __forceinline__ void rot_pre(float sr[16], float si[16], const float* __restrict__ u) {
    const float u00r = u[0], u00i = u[1], u01r = u[2], u01i = u[3];
    const float u10r = u[4], u10i = u[5], u11r = u[6], u11i = u[7];
#pragma unroll
    for (int i = 0; i < 16; ++i) {
        if (i & M) continue;
        const int j = i | M;
        float ar = sr[i], ai = si[i], br = sr[j], bi = si[j];
        sr[i] = u00r * ar - u00i * ai + u01r * br - u01i * bi;
        si[i] = u00r * ai + u00i * ar + u01r * bi + u01i * br;
        sr[j] = u10r * ar - u10i * ai + u11r * br - u11i * bi;
        si[j] = u10r * ai + u10i * ar + u11r * bi + u11i * br;
    }
}

__device__ __forceinline__ void zexp_g(const float sr[16], const float si[16], float z[4]) {
    float p[16];
#pragma unroll
    for (int i = 0; i < 16; ++i) p[i] = sr[i] * sr[i] + si[i] * si[i];
    z[0] = z[1] = z[2] = z[3] = 0.f;
#pragma unroll
    for (int i = 0; i < 16; ++i) {
        z[0] += (i & 8) ? -p[i] : p[i];
        z[1] += (i & 4) ? -p[i] : p[i];
        z[2] += (i & 2) ? -p[i] : p[i];
        z[3] += (i & 1) ? -p[i] : p[i];
    }
}

// ---------------- setup: rot matrices + fused output matrix -----------------
// rotbuf: [0..15] ent (2l x 2sub x 4w), [16..23] att (2l x 4w), [24..35] path (3l x 4w)
__global__ void k_setup(const float* __restrict__ entp, const float* __restrict__ attqp,
                        const float* __restrict__ pparm,
                        const float* __restrict__ outW, const float* __restrict__ outb,
                        const float* __restrict__ poW, const float* __restrict__ pob,
                        float* __restrict__ rotbuf, float* __restrict__ M,
                        float* __restrict__ v) {
    const int t = threadIdx.x;
    if (t < 36) {
        const float* p;
        if (t < 16)      p = entp  + t * 3;
        else if (t < 24) p = attqp + (t - 16) * 3;
        else             p = pparm + (t - 24) * 3;
        float phi = p[0], theta = p[1], omega = p[2];
        float st, ct; sincosf(0.5f * theta, &st, &ct);
        float sp, cp; sincosf(0.5f * (phi + omega), &sp, &cp);
        float sm, cm; sincosf(0.5f * (phi - omega), &sm, &cm);
        float* u = rotbuf + t * 8;
        u[0] =  ct * cp;  u[1] = -ct * sp;
        u[2] = -st * cm;  u[3] = -st * sm;
        u[4] =  st * cm;  u[5] = -st * sm;
        u[6] =  ct * cp;  u[7] =  ct * sp;
    } else if (t >= 64 && t < 192) {
        int t2 = t - 64;
        int o = t2 >> 2, i = t2 & 3;
        float acc = 0.f;
        for (int j = 0; j < 128; ++j) acc += outW[o * 128 + j] * poW[j * 4 + i];
        M[t2] = acc;
    } else if (t >= 192 && t < 224) {
        int o = t - 192;
        float acc = outb[o];
        for (int j = 0; j < 128; ++j) acc += outW[o * 128 + j] * pob[j];
        v[o] = acc;
    }
}

// ---------------- dst binning (edge_index layer-invariant: built once) -------

__global__ void k_hist(const int* __restrict__ ei, int* __restrict__ cnt, int E, int EP) {
    int e = blockIdx.x * blockDim.x + threadIdx.x;
    if (e >= EP) return;
    int d_ = (e < E) ? ei[E + e] : e - E;
    atomicAdd(&cnt[d_], 1);
}

__global__ void k_scan(const int* __restrict__ cnt, int* __restrict__ off,
                       int* __restrict__ cur, int N) {
    __shared__ int tot[1024];
    const int t = threadIdx.x;
    const int chunk = (N + 1023) >> 10;
    const int s0 = t * chunk;
    const int s1 = min(s0 + chunk, N);
    int sum = 0;
    for (int i = s0; i < s1; ++i) sum += cnt[i];
    tot[t] = sum;
    __syncthreads();
    for (int d = 1; d < 1024; d <<= 1) {
        int v = (t >= d) ? tot[t - d] : 0;
        __syncthreads();
        tot[t] += v;
        __syncthreads();
    }
    int run = (t == 0) ? 0 : tot[t - 1];
    for (int i = s0; i < s1; ++i) {
        off[i] = run; cur[i] = run;
        run += cnt[i];
    }
}

__global__ void k_fill(const int* __restrict__ ei, int* __restrict__ cur,
                       int* __restrict__ srcs, int* __restrict__ dsts, int E, int EP) {
    int e = blockIdx.x * blockDim.x + threadIdx.x;
    if (e >= EP) return;
    int s_, d_;
    if (e < E) { s_ = ei[e]; d_ = ei[E + e]; } else { s_ = d_ = e - E; }
    int pos = atomicAdd(&cur[d_], 1);
    srcs[pos] = s_;
    dsts[pos] = d_;
}

// ---------------- node-side kernels -----------------------------------------

// h = relu(x @ W_in^T + b_in); 16 nodes/block, 256 threads (4 waves)
#define XS 68
__global__ __launch_bounds__(256) void k_in(
        const float* __restrict__ x, const float* __restrict__ W,
        const float* __restrict__ b, float* __restrict__ h, int N) {
    __shared__ float xs[16 * XS];
    const int base = blockIdx.x * 16;
    const int tid = threadIdx.x;
    for (int idx = tid; idx < 16 * 64; idx += 256) {
        int n = base + (idx >> 6);
        xs[(idx >> 6) * XS + (idx & 63)] = (n < N) ? x[(size_t)n * 64 + (idx & 63)] : 0.f;
    }
    __syncthreads();
    const int o  = tid & 127;
    const int nh = tid >> 7;   // 0..1 -> nodes nh*8 .. +7
    float acc[8];
#pragma unroll
    for (int i = 0; i < 8; ++i) acc[i] = 0.f;
    const float4* w4 = (const float4*)(W + o * 64);
    for (int c4 = 0; c4 < 16; ++c4) {
        float4 w = w4[c4];
#pragma unroll
        for (int i = 0; i < 8; ++i) {
            float4 hv = *(const float4*)&xs[(nh * 8 + i) * XS + c4 * 4];
            acc[i] += w.x * hv.x + w.y * hv.y + w.z * hv.z + w.w * hv.w;
        }
    }
    const float bb = b[o];
#pragma unroll
    for (int i = 0; i < 8; ++i) {
        int node = base + nh * 8 + i;
        if (node < N) h[(size_t)node * 128 + o] = fmaxf(acc[i] + bb, 0.f);
    }
}

// fused per-node layer kernel: x_comb (+qproj of inline ent-circuit), q/k (c,s)
#define HS 132
__global__ __launch_bounds__(256) void k_lin(
        const float* __restrict__ h,
        const float* __restrict__ linW, const float* __restrict__ linb,
        const float* __restrict__ qpW, const float* __restrict__ qpb,
        const float* __restrict__ aqW, const float* __restrict__ aqb,
        const float* __restrict__ akW, const float* __restrict__ akb,
        const float* __restrict__ rotE,
        float* __restrict__ xcomb, float* __restrict__ qbuf,
        float* __restrict__ kbuf, int N) {
    __shared__ float hs[16 * HS];
    __shared__ float zS[16 * 4];
    const int base = blockIdx.x * 16;
    const int tid = threadIdx.x;
    for (int idx = tid; idx < 16 * 128; idx += 256) {
        int n = base + (idx >> 7);
        hs[(idx >> 7) * HS + (idx & 127)] = (n < N) ? h[(size_t)n * 128 + (idx & 127)] : 0.f;
    }
    __syncthreads();

    const int o  = tid & 127;
    const int nh = tid >> 7;
    float acc[8];
#pragma unroll
    for (int i = 0; i < 8; ++i) acc[i] = 0.f;
    const float4* w4 = (const float4*)(linW + o * 128);
    for (int c4 = 0; c4 < 32; ++c4) {
        float4 w = w4[c4];
#pragma unroll
        for (int i = 0; i < 8; ++i) {
            float4 hv = *(const float4*)&hs[(nh * 8 + i) * HS + c4 * 4];
            acc[i] += w.x * hv.x + w.y * hv.y + w.z * hv.z + w.w * hv.w;
        }
    }

    // q/k: threads 0..127 -> 16 nodes x (4 q + 4 k); rows 0..15, stride 132 -> no conflicts
    if (tid < 128) {
        const int nl = tid >> 3;
        const int which = tid & 7;
        const int qi = which & 3;
        const float4* Wp4 = (const float4*)(((which < 4) ? aqW : akW) + qi * 128);
        float dot = (which < 4) ? aqb[qi] : akb[qi];
        for (int c4 = 0; c4 < 32; ++c4) {
            float4 w = Wp4[c4];
            float4 hv = *(const float4*)&hs[nl * HS + c4 * 4];
            dot += w.x * hv.x + w.y * hv.y + w.z * hv.z + w.w * hv.w;
        }
        int node = base + nl;
        if (node < N) {
            float half = fast_tanh(dot) * (0.5f * PI_HALF);
            float s, c; __sincosf(half, &s, &c);
            float* dst = ((which < 4) ? qbuf : kbuf) + (size_t)node * 8 + qi * 2;
            dst[0] = c; dst[1] = s;
        }
    } else if (tid < 144) {
        // entangle circuit for node (tid-128), inline (replaces k_ent kernel)
        const int en = tid - 128;
        float4 hv = *(const float4*)&hs[en * HS];
        float sr[16], si[16];
        init_state(sr, si);
        { float s, c; __sincosf(fast_tanh(hv.x) * (0.5f * PI_HALF), &s, &c); ry_g<8>(sr, si, c, s); }
        { float s, c; __sincosf(fast_tanh(hv.y) * (0.5f * PI_HALF), &s, &c); ry_g<4>(sr, si, c, s); }
        { float s, c; __sincosf(fast_tanh(hv.z) * (0.5f * PI_HALF), &s, &c); ry_g<2>(sr, si, c, s); }
        { float s, c; __sincosf(fast_tanh(hv.w) * (0.5f * PI_HALF), &s, &c); ry_g<1>(sr, si, c, s); }
#pragma unroll
        for (int l = 0; l < 2; ++l) {
            cnot_g<8, 4>(sr, si); cnot_g<4, 2>(sr, si); cnot_g<2, 1>(sr, si);
            const float* P = rotE + l * 32;
            rot_pre<8>(sr, si, P);
            rot_pre<4>(sr, si, P + 8);
            rot_pre<2>(sr, si, P + 16);
            rot_pre<1>(sr, si, P + 24);
            cnot_g<8, 1>(sr, si);  // CNOT(0, 3)
        }
        float z[4]; zexp_g(sr, si, z);
        zS[en * 4 + 0] = z[0]; zS[en * 4 + 1] = z[1];
        zS[en * 4 + 2] = z[2]; zS[en * 4 + 3] = z[3];
    }
    __syncthreads();

    const float bb = linb[o] + qpb[o];
    const float4 qw = *(const float4*)(qpW + o * 4);
#pragma unroll
    for (int i = 0; i < 8; ++i) {
        int node = base + nh * 8 + i;
        if (node < N) {
            float4 z = *(const float4*)&zS[(nh * 8 + i) * 4];
            xcomb[(size_t)node * 128 + o] = acc[i] + bb
                + qw.x * z.x + qw.y * z.y + qw.z * z.z + qw.w * z.w;
        }
    }
}

// attention circuit per slot (dst-binned order): coalesced src/dst/escore
__global__ void k_att(const float* __restrict__ qb, const float* __restrict__ kb,
                      const int* __restrict__ srcs, const int* __restrict__ dsts,
                      const float* __restrict__ RA, float* __restrict__ escore,
                      float* __restrict__ sumexp, int EP) {
    __shared__ float red[4];
    int p = blockIdx.x * blockDim.x + threadIdx.x;
    float ex = 0.f;
    if (p < EP) {
        int s_ = srcs[p], d_ = dsts[p];
        float4 qa = *(const float4*)&qb[(size_t)s_ * 8];
        float4 qc = *(const float4*)&qb[(size_t)s_ * 8 + 4];
        float4 ka = *(const float4*)&kb[(size_t)d_ * 8];
        float4 kc = *(const float4*)&kb[(size_t)d_ * 8 + 4];
        float sr[16], si[16];
        init_state(sr, si);
        ry_g<8>(sr, si, qa.x, qa.y);
        ry_g<4>(sr, si, qa.z, qa.w);
        ry_g<2>(sr, si, qc.x, qc.y);
        ry_g<1>(sr, si, qc.z, qc.w);
        had_g<8>(sr, si); had_g<4>(sr, si); had_g<2>(sr, si); had_g<1>(sr, si);
        cry_g<8, 4>(sr, si, ka.x, ka.y);
        cry_g<4, 2>(sr, si, ka.z, ka.w);
        cry_g<2, 1>(sr, si, kc.x, kc.y);
        cry_g<1, 8>(sr, si, kc.z, kc.w);
        rot_pre<8>(sr, si, RA);
        rot_pre<4>(sr, si, RA + 8);
        rot_pre<2>(sr, si, RA + 16);
        rot_pre<1>(sr, si, RA + 24);
        float z[4]; zexp_g(sr, si, z);
        float sc = 0.25f * (z[0] + z[1] + z[2] + z[3]);
        ex = __expf(sc);
        escore[p] = ex;
    }
    // wave reduce + cross-wave via LDS
    float w = ex;
#pragma unroll
    for (int d = 32; d > 0; d >>= 1) w += __shfl_down(w, d, 64);
    if ((threadIdx.x & 63) == 0) red[threadIdx.x >> 6] = w;
    __syncthreads();
    if (threadIdx.x == 0)
        atomicAdd(sumexp, red[0] + red[1] + red[2] + red[3]);
}

// one block per dst: h[dst,:] = relu( invS * sum_slot escore[slot]*xcomb[srcs[slot],:] )
__global__ void k_gather(const float* __restrict__ xcomb, const int* __restrict__ srcs,
                         const float* __restrict__ escore, const int* __restrict__ off,
                         const int* __restrict__ cnt, const float* __restrict__ sumexp,
                         float* __restrict__ h) {
    __shared__ int sS[128];
    __shared__ float wS[128];
    const int b = blockIdx.x;
    const int tid = threadIdx.x;  // 128
    const int start = off[b];
    const int num = cnt[b];
    float acc = 0.f;
    for (int base = 0; base < num; base += 128) {
        int m = min(128, num - base);
        if (tid < m) {
            sS[tid] = srcs[start + base + tid];
            wS[tid] = escore[start + base + tid];
        }
        __syncthreads();
        for (int i = 0; i < m; ++i)
            acc += wS[i] * xcomb[(size_t)sS[i] * 128 + tid];
        __syncthreads();
    }
    const float invS = __builtin_amdgcn_rcpf(sumexp[0]);
    h[(size_t)b * 128 + tid] = fmaxf(acc * invS, 0.f);
}

// fused: pq dots + path circuit + out = M@z + v; 64 nodes/block, 256 threads
__global__ __launch_bounds__(256) void k_path(
        const float* __restrict__ h, const float* __restrict__ piW,
        const float* __restrict__ pib, const float* __restrict__ RP,
        const float* __restrict__ M, const float* __restrict__ v,
        float* __restrict__ out, int N) {
    __shared__ float hs[64 * HS];
    __shared__ float pqS[64 * 9];
    __shared__ float zS[64 * 4];
    __shared__ float MS[128];
    __shared__ float vS[32];
    const int base = blockIdx.x * 64;
    const int tid = threadIdx.x;
    if (tid < 128) MS[tid] = M[tid];
    else if (tid < 160) vS[tid - 128] = v[tid - 128];
    for (int idx = tid; idx < 64 * 128; idx += 256) {
        int n = base + (idx >> 7);
        hs[(idx >> 7) * HS + (idx & 127)] = (n < N) ? h[(size_t)n * 128 + (idx & 127)] : 0.f;
    }
    __syncthreads();
    // pq dots: 256 threads = 64 nodes x 4 outputs
    {
        const int nl = tid >> 2;
        const int i  = tid & 3;
        float dot = pib[i];
        const float4* w4 = (const float4*)(piW + i * 128);
        for (int c4 = 0; c4 < 32; ++c4) {
            float4 w = w4[c4];
            float4 hv = *(const float4*)&hs[nl * HS + c4 * 4];
            dot += w.x * hv.x + w.y * hv.y + w.z * hv.z + w.w * hv.w;
        }
        float half = fast_tanh(dot) * (0.5f * PI_HALF);
        float s, c; __sincosf(half, &s, &c);
        pqS[nl * 9 + i * 2]     = c;
        pqS[nl * 9 + i * 2 + 1] = s;
    }
    __syncthreads();
    if (tid < 64) {
        const float* p = pqS + tid * 9;
        float sr[16], si[16];
        init_state(sr, si);
        had_g<8>(sr, si); had_g<4>(sr, si); had_g<2>(sr, si); had_g<1>(sr, si);
        ry_g<8>(sr, si, p[0], p[1]);
        ry_g<4>(sr, si, p[2], p[3]);
        ry_g<2>(sr, si, p[4], p[5]);
        ry_g<1>(sr, si, p[6], p[7]);
#pragma unroll
        for (int l = 0; l < 3; ++l) {
            const float* P = RP + l * 32;
            rot_pre<8>(sr, si, P);
            rot_pre<4>(sr, si, P + 8);
            rot_pre<2>(sr, si, P + 16);
            rot_pre<1>(sr, si, P + 24);
            cnot_g<8, 4>(sr, si); cnot_g<4, 2>(sr, si); cnot_g<2, 1>(sr, si);
        }
        float z[4]; zexp_g(sr, si, z);
        zS[tid * 4 + 0] = z[0]; zS[tid * 4 + 1] = z[1];
        zS[tid * 4 + 2] = z[2]; zS[tid * 4 + 3] = z[3];
    }
    __syncthreads();
#pragma unroll
    for (int k = 0; k < 8; ++k) {
        int flat = k * 256 + tid;
        int nl = flat >> 5;
        int o = flat & 31;
        int node = base + nl;
        if (node < N) {
            out[(size_t)node * 32 + o] = vS[o]
                + MS[o * 4 + 0] * zS[nl * 4 + 0] + MS[o * 4 + 1] * zS[nl * 4 + 1]
                + MS[o * 4 + 2] * zS[nl * 4 + 2] + MS[o * 4 + 3] * zS[nl * 4 + 3];
        }
    }
}

// ---------------- launch ----------------------------------------------------

extern "C" void kernel_launch(void* const* d_in, const int* in_sizes, int n_in,
                              void* d_out, int out_size, void* d_ws, size_t ws_size,
                              hipStream_t stream) {
    const float* x     = (const float*)d_in[0];
    const float* W_in  = (const float*)d_in[1];
    const float* b_in  = (const float*)d_in[2];
    const float* linW  = (const float*)d_in[3];
    const float* linb  = (const float*)d_in[4];
    const float* qpW   = (const float*)d_in[5];
    const float* qpb   = (const float*)d_in[6];
    const float* entp  = (const float*)d_in[7];
    const float* aqW   = (const float*)d_in[8];
    const float* aqb   = (const float*)d_in[9];
    const float* akW   = (const float*)d_in[10];
    const float* akb   = (const float*)d_in[11];
    const float* attqp = (const float*)d_in[12];
    const float* pparm = (const float*)d_in[13];
    const float* piW   = (const float*)d_in[14];
    const float* pib   = (const float*)d_in[15];
    const float* poW   = (const float*)d_in[16];
    const float* pob   = (const float*)d_in[17];
    const float* outW  = (const float*)d_in[18];
    const float* outb  = (const float*)d_in[19];
    const int*   ei    = (const int*)d_in[20];

    const int N  = in_sizes[0] / 64;   // 20000
    const int E  = in_sizes[20] / 2;   // 300000
    const int EP = E + N;              // self-loops appended

    float* ws     = (float*)d_ws;
    float* h      = ws;
    float* xcomb  = h      + (size_t)N * 128;
    float* qbuf   = xcomb  + (size_t)N * 128;
    float* kbuf   = qbuf   + (size_t)N * 8;
    float* escore = kbuf   + (size_t)N * 8;
    float* rotbuf = escore + EP;
    float* Mm     = rotbuf + 36 * 8;
    float* vv     = Mm + 128;
    int*   cnt    = (int*)(vv + 32);
    float* sumexp = (float*)(cnt + N);   // 2 slots, zeroed together with cnt
    int*   off    = (int*)(sumexp + 4);
    int*   cur    = off + N;
    int*   srcs   = cur + N;
    int*   dsts   = srcs + EP;

    const float* rotE = rotbuf;          // 16 matrices
    const float* rotA = rotbuf + 128;    // 8 matrices
    const float* rotP = rotbuf + 192;    // 12 matrices

    const int nb16 = (N + 15) / 16;
    const int ebl  = (EP + 255) / 256;

    hipMemsetAsync(cnt, 0, (size_t)(N + 4) * sizeof(int), stream);
    k_hist<<<ebl, 256, 0, stream>>>(ei, cnt, E, EP);
    k_scan<<<1, 1024, 0, stream>>>(cnt, off, cur, N);
    k_fill<<<ebl, 256, 0, stream>>>(ei, cur, srcs, dsts, E, EP);
    k_setup<<<1, 256, 0, stream>>>(entp, attqp, pparm, outW, outb, poW, pob,
                                   rotbuf, Mm, vv);
    k_in<<<nb16, 256, 0, stream>>>(x, W_in, b_in, h, N);

    for (int l = 0; l < 2; ++l) {
        k_lin<<<nb16, 256, 0, stream>>>(h,
            linW + (size_t)l * 128 * 128, linb + l * 128,
            qpW + (size_t)l * 128 * 4, qpb + l * 128,
            aqW + (size_t)l * 4 * 128, aqb + l * 4,
            akW + (size_t)l * 4 * 128, akb + l * 4,
            rotE + l * 64, xcomb, qbuf, kbuf, N);
        k_att<<<ebl, 256, 0, stream>>>(qbuf, kbuf, srcs, dsts, rotA + l * 32,
                                       escore, sumexp + l, EP);
        k_gather<<<N, 128, 0, stream>>>(xcomb, srcs, escore, off, cnt, sumexp + l, h);
    }

    k_path<<<(N + 63) / 64, 256, 0, stream>>>(h, piW, pib, rotP, Mm, vv,
                                              (float*)d_out, N);
}